// Round 4
// baseline (1909.517 us; speedup 1.0000x reference)
//
#include <hip/hip_runtime.h>
#include <math.h>

#define MUL    16
#define CIN    64
#define COUT   144
#define SDIM   40
#define SP     64000
#define NTAP   125
#define KW_ELEMS (NTAP*CIN*COUT)

// xp layout: ushort xph/xpl[b][x][ich][QROWS][32ch]
#define QROWS  1940
#define PL_STRIDE (QROWS*32)             // ushorts per (b,x,ich) plane = 62080
#define XP_USHORT (2*40*2*PL_STRIDE)     // 9,932,800 per array
#define KWB_SHORTS (NTAP*2*9*64*8)       // 1,152,000 per array

// conv tiling
#define NBLK   128
#define WIN    308                        // 128 + 4*44 + 4
#define NCHUNK 14
#define LAST_TILE 109                     // valid positions p < 1760 = 110 tiles

// ---------------- constants ----------------
#define SQ3    1.7320508075688772
#define SQ5    2.23606797749979
#define PW0    0.17677669529663687
#define PW1    0.25
#define PW2    0.3952847075210474
#define PW0_D3 0.10206207261596575
#define PW1_D3 0.14433756729740643
#define PW2_D5 0.17677669529663687
#define C_S    0.3651483716701107
#define C_H    0.31622776601683794

__device__ __constant__ double dC112[3][3][5] = {
  { {0.0, 0.0, -0.5*C_S, 0.0, -C_H},
    {0.0, C_H, 0.0,      0.0, 0.0 },
    {C_H, 0.0, 0.0,      0.0, 0.0 } },
  { {0.0, C_H, 0.0, 0.0, 0.0},
    {0.0, 0.0, C_S, 0.0, 0.0},
    {0.0, 0.0, 0.0, C_H, 0.0} },
  { {C_H, 0.0, 0.0, 0.0, 0.0},
    {0.0, 0.0, 0.0, C_H, 0.0},
    {0.0, 0.0, -0.5*C_S, 0.0, C_H} }
};

typedef __attribute__((ext_vector_type(4))) float f32x4;
typedef __attribute__((ext_vector_type(8))) short short8;
typedef __attribute__((ext_vector_type(8))) __bf16 bf16x8;

static __device__ __forceinline__ unsigned short f2bf(float f) {
  unsigned int u = __float_as_uint(f);
  unsigned int r = (u + 0x7fffu + ((u >> 16) & 1u)) >> 16;
  return (unsigned short)r;
}
static __device__ __forceinline__ float bf2f(unsigned short h) {
  return __uint_as_float(((unsigned int)h) << 16);
}
static __device__ __forceinline__ bf16x8 as_bf(short8 v) {
  union { short8 s; bf16x8 b; } u; u.s = v; return u.b;
}
static __device__ __forceinline__ short8 u4_to_s8(uint4 v) {
  union { uint4 u; short8 s; } c; c.u = v; return c.s;
}

// ---------------- weight-value function ----------------
static __device__ double kw_value(int tap, int i, int o, const float* __restrict__ w_tp) {
  int kz = tap % 5, ky = (tap / 5) % 5, kx = tap / 25;
  double lx = -1.0 + 0.5 * kx, ly = -1.0 + 0.5 * ky, lz = -1.0 + 0.5 * kz;
  double d = sqrt(lx*lx + ly*ly + lz*lz);
  double emb[5];
  #pragma unroll
  for (int t = 0; t < 5; ++t) {
    double diff = (d - (t + 1) / 6.0) * 6.0;
    double a = diff + 1.0, bb = 1.0 - diff;
    double sa = (a  > 0.0) ? exp(-1.0 / a)  : 0.0;
    double sb = (bb > 0.0) ? exp(-1.0 / bb) : 0.0;
    emb[t] = 1.14136 * exp(2.0) * sa * sb;
  }
  double inv = 1.0 / fmax(d, 1e-12);
  double ux = lx * inv, uy = ly * inv, uz = lz * inv;
  double sh1[3] = { SQ3 * ux, SQ3 * uy, SQ3 * uz };
  double sh2[5] = { SQ5 * SQ3 * ux * uz,
                    SQ5 * SQ3 * ux * uy,
                    SQ5 * (uy*uy - 0.5*(ux*ux + uz*uz)),
                    SQ5 * SQ3 * uy * uz,
                    SQ5 * 0.5 * SQ3 * (uz*uz - ux*ux) };

  #define WVAL(n, u, w) ({                                              \
      int base_ = (n)*256 + (u)*16 + (w);                               \
      double a_ = 0.0;                                                  \
      _Pragma("unroll")                                                 \
      for (int t_ = 0; t_ < 5; ++t_)                                    \
        a_ += emb[t_] * (double)w_tp[t_*1792 + base_];                  \
      (a_ * 0.08944271909999159); })

  double val;
  if (i < MUL) {
    int u = i;
    if (o < MUL) {
      val = PW0 * WVAL(0, u, o);
    } else if (o < 4 * MUL) {
      int w = (o - 16) / 3, k = (o - 16) % 3;
      val = PW1_D3 * sh1[k] * WVAL(1, u, w);
    } else {
      int w = (o - 64) / 5, k = (o - 64) % 5;
      val = PW2_D5 * sh2[k] * WVAL(2, u, w);
    }
  } else {
    int u = (i - 16) / 3, ii = (i - 16) % 3;
    if (o < MUL) {
      val = PW0_D3 * sh1[ii] * WVAL(4, u, o);
    } else if (o < 4 * MUL) {
      int w = (o - 16) / 3, k = (o - 16) % 3;
      double v = 0.0;
      if (ii == k) v += PW1_D3 * WVAL(3, u, w);
      double cs = 0.0;
      #pragma unroll
      for (int j = 0; j < 5; ++j) cs += dC112[ii][k][j] * sh2[j];
      v += PW1 * cs * WVAL(6, u, w);
      val = v;
    } else {
      int w = (o - 64) / 5, k = (o - 64) % 5;
      double cs = 0.0;
      #pragma unroll
      for (int j = 0; j < 3; ++j) cs += dC112[ii][j][k] * sh1[j];
      val = PW2 * cs * WVAL(5, u, w);
    }
  }
  return val;
}

// ---------------- MFMA-fragment weight builder ----------------
__global__ void build_kwb(const float* __restrict__ w_tp,
                          unsigned short* __restrict__ kwbh,
                          unsigned short* __restrict__ kwbl) {
  int gid = blockIdx.x * 256 + threadIdx.x;
  if (gid >= NTAP * 2 * 9 * 64) return;
  int lane = gid & 63;
  int t1 = gid >> 6;
  int mt = t1 % 9;
  int t2 = t1 / 9;
  int ich = t2 & 1;
  int tap = t2 >> 1;
  int o = mt * 16 + (lane & 15);
  unsigned short h8[8], l8[8];
  #pragma unroll
  for (int j = 0; j < 8; ++j) {
    int i = ich * 32 + 8 * (lane >> 4) + j;
    float v = (float)kw_value(tap, i, o, w_tp);
    unsigned short h = f2bf(v);
    h8[j] = h;
    l8[j] = f2bf(v - bf2f(h));
  }
  #pragma unroll
  for (int j = 0; j < 8; ++j) {
    kwbh[(size_t)gid * 8 + j] = h8[j];
    kwbl[(size_t)gid * 8 + j] = l8[j];
  }
}

// ---------------- x pack: transpose to channel-contiguous hi/lo planes ----------------
// grid: ((b*40+xx)*2+ich)*45 + qy ; qy==44 zero-fills tail rows
__global__ void xp_pack2(const float* __restrict__ x,
                         unsigned short* __restrict__ xph,
                         unsigned short* __restrict__ xpl) {
  __shared__ float tile[32][40];
  int bidx = blockIdx.x;
  int qy = bidx % 45;
  int t = bidx / 45;
  int ich = t & 1; t >>= 1;
  int xx = t % 40;
  int b = t / 40;
  int tid = threadIdx.x;
  size_t plane = ((size_t)(b * 40 + xx) * 2 + ich) * PL_STRIDE;
  unsigned int* dh = (unsigned int*)(xph) + plane / 2;
  unsigned int* dl = (unsigned int*)(xpl) + plane / 2;

  if (qy == 44) {               // zero rows 1936..1939 (4 rows * 16 u32)
    if (tid < 64) { dh[1936 * 16 + tid] = 0u; dl[1936 * 16 + tid] = 0u; }
    return;
  }
  int y = qy - 2;
  for (int idx = tid; idx < 32 * 40; idx += 256) {
    int c = idx / 40, z = idx % 40;
    float v = 0.f;
    if (y >= 0 && y < 40)
      v = x[(((size_t)(b * 64 + ich * 32 + c) * 40 + xx) * 40 + y) * 40 + z];
    tile[c][z] = v;
  }
  __syncthreads();
  for (int idx = tid; idx < 44 * 16; idx += 256) {
    int qz = idx / 16, c2 = idx % 16;
    int z = qz - 2;
    float v0 = 0.f, v1 = 0.f;
    if (z >= 0 && z < 40) { v0 = tile[2 * c2][z]; v1 = tile[2 * c2 + 1][z]; }
    unsigned short h0 = f2bf(v0), h1 = f2bf(v1);
    unsigned short l0 = f2bf(v0 - bf2f(h0)), l1 = f2bf(v1 - bf2f(h1));
    int q = qy * 44 + qz;
    dh[q * 16 + c2] = ((unsigned int)h1 << 16) | h0;
    dl[q * 16 + c2] = ((unsigned int)l1 << 16) | l0;
  }
}

// ---------------- self-connection ----------------
__global__ void sc_kernel(const float* __restrict__ x,
                          const float* __restrict__ w0,
                          const float* __restrict__ w1,
                          float* __restrict__ out) {
  int gid = blockIdx.x * 256 + threadIdx.x;
  if (gid >= 2 * SP) return;
  int b = gid / SP, p = gid % SP;
  const float* xb = x + (size_t)b * CIN * SP + p;
  float xv[64];
  #pragma unroll
  for (int c = 0; c < 64; ++c) xv[c] = xb[(size_t)c * SP];
  float* ob = out + (size_t)b * COUT * SP + p;
  #pragma unroll
  for (int w = 0; w < 16; ++w) {
    float s = 0.f;
    #pragma unroll
    for (int u = 0; u < 16; ++u) s = fmaf(w0[u * 16 + w], xv[u], s);
    ob[(size_t)w * SP] = 0.25f * s;
  }
  #pragma unroll
  for (int w = 0; w < 16; ++w) {
    #pragma unroll
    for (int i2 = 0; i2 < 3; ++i2) {
      float s = 0.f;
      #pragma unroll
      for (int u = 0; u < 16; ++u) s = fmaf(w1[u * 16 + w], xv[16 + u * 3 + i2], s);
      ob[(size_t)(16 + w * 3 + i2) * SP] = 0.25f * s;
    }
  }
  #pragma unroll
  for (int o = 64; o < 144; ++o) ob[(size_t)o * SP] = 0.f;
}

// ---------------- MFMA conv: 2 waves, nt=4/wave, N=128/block ----------------
// grid = 1120 = 8 XCD * 140; logical = bX*14 + chunk
__global__ __launch_bounds__(128, 2)
void conv_mfma2(const unsigned short* __restrict__ xph,
                const unsigned short* __restrict__ xpl,
                const unsigned short* __restrict__ kwbh,
                const unsigned short* __restrict__ kwbl,
                float* __restrict__ out) {
  __shared__ __align__(16) unsigned int xh32[WIN * 16];   // 19.7 KB
  __shared__ __align__(16) unsigned int xl32[WIN * 16];   // 19.7 KB

  int tid = threadIdx.x;
  int bid = blockIdx.x;
  int logical = (bid & 7) * 140 + (bid >> 3);     // XCD-grouped
  int bX = logical / NCHUNK;
  int chunk = logical - bX * NCHUNK;
  int b = bX / 40, X = bX % 40;
  int p0 = chunk * NBLK;

  int wid = tid >> 6, lane = tid & 63;
  int l15 = lane & 15, g = lane >> 4;

  int tb[4]; bool realt[4]; int ptile[4];
  #pragma unroll
  for (int nt = 0; nt < 4; ++nt) {
    int t = chunk * 8 + wid * 4 + nt;
    realt[nt] = (t <= LAST_TILE);
    if (t > LAST_TILE) t = LAST_TILE;
    ptile[nt] = t;
    tb[nt] = t * 16 + l15 - p0;          // LDS-relative base row
  }

  f32x4 acc[9][4];
  #pragma unroll
  for (int mt = 0; mt < 9; ++mt)
    #pragma unroll
    for (int nt = 0; nt < 4; ++nt) acc[mt][nt] = (f32x4)0.f;

  #pragma unroll 1
  for (int dx = 0; dx < 5; ++dx) {
    int xs = X + dx - 2;
    if (xs < 0 || xs >= 40) continue;     // uniform
    #pragma unroll 1
    for (int ich = 0; ich < 2; ++ich) {
      __syncthreads();
      {
        size_t plane = ((size_t)(b * 40 + xs) * 2 + ich) * PL_STRIDE;
        const unsigned int* sh = (const unsigned int*)xph + plane / 2 + (size_t)p0 * 16;
        const unsigned int* sl = (const unsigned int*)xpl + plane / 2 + (size_t)p0 * 16;
        int qmax = QROWS - p0;
        #pragma unroll 1
        for (int idx = tid; idx < WIN * 4; idx += 128) {
          int q = idx >> 2, s4 = idx & 3;
          uint4 vh = make_uint4(0, 0, 0, 0), vl = make_uint4(0, 0, 0, 0);
          if (q < qmax) {
            vh = *(const uint4*)(sh + q * 16 + s4 * 4);
            vl = *(const uint4*)(sl + q * 16 + s4 * 4);
          }
          int dst = q * 16 + ((s4 ^ ((q >> 1) & 3)) << 2);
          *(uint4*)(xh32 + dst) = vh;
          *(uint4*)(xl32 + dst) = vl;
        }
      }
      __syncthreads();
      #pragma unroll 1
      for (int dy = 0; dy < 5; ++dy) {
        #pragma unroll 1
        for (int dz = 0; dz < 5; ++dz) {
          int tap = (dx * 5 + dy) * 5 + dz;
          int shift = dy * 44 + dz;
          short8 bh[4], bl[4];
          #pragma unroll
          for (int nt = 0; nt < 4; ++nt) {
            int q = tb[nt] + shift;
            int off = q * 16 + (((g ^ ((q >> 1) & 3))) << 2);
            bh[nt] = u4_to_s8(*(const uint4*)(xh32 + off));
            bl[nt] = u4_to_s8(*(const uint4*)(xl32 + off));
          }
          const short8* ah_p = (const short8*)kwbh + ((size_t)(tap * 2 + ich) * 9) * 64 + lane;
          const short8* al_p = (const short8*)kwbl + ((size_t)(tap * 2 + ich) * 9) * 64 + lane;
          #pragma unroll
          for (int mt = 0; mt < 9; ++mt) {
            short8 ah = ah_p[mt * 64];
            short8 al = al_p[mt * 64];
            #pragma unroll
            for (int nt = 0; nt < 4; ++nt) {
              acc[mt][nt] = __builtin_amdgcn_mfma_f32_16x16x32_bf16(as_bf(ah), as_bf(bh[nt]), acc[mt][nt], 0, 0, 0);
              acc[mt][nt] = __builtin_amdgcn_mfma_f32_16x16x32_bf16(as_bf(ah), as_bf(bl[nt]), acc[mt][nt], 0, 0, 0);
              acc[mt][nt] = __builtin_amdgcn_mfma_f32_16x16x32_bf16(as_bf(al), as_bf(bh[nt]), acc[mt][nt], 0, 0, 0);
            }
          }
        }
      }
    }
  }

  float* ob = out + (size_t)b * COUT * SP + (size_t)X * 1600;
  #pragma unroll
  for (int mt = 0; mt < 9; ++mt) {
    #pragma unroll
    for (int nt = 0; nt < 4; ++nt) {
      if (!realt[nt]) continue;
      int p = ptile[nt] * 16 + l15;
      int y = p / 44, z = p - y * 44;
      if (z < 40) {
        #pragma unroll
        for (int r = 0; r < 4; ++r) {
          int o = mt * 16 + g * 4 + r;
          ob[(size_t)o * SP + y * 40 + z] += 0.1f * acc[mt][nt][r];
        }
      }
    }
  }
}

// ---------------- fp32 fallback path ----------------
__global__ void build_kw(const float* __restrict__ w_tp, float* __restrict__ kw) {
  int gid = blockIdx.x * 256 + threadIdx.x;
  if (gid >= KW_ELEMS) return;
  int o   = gid % COUT;
  int i   = (gid / COUT) % CIN;
  int tap = gid / (COUT * CIN);
  kw[gid] = (float)kw_value(tap, i, o, w_tp);
}

#define IC 8
__global__ __launch_bounds__(256, 4)
void conv_kernel(const float* __restrict__ x,
                 const float* __restrict__ kw,
                 float* __restrict__ out) {
  __shared__ float x_lds[IC][6][44];
  int tid = threadIdx.x;
  int bid = blockIdx.x;
  int tileY = bid % 20;
  int X     = (bid / 20) % SDIM;
  int b     = bid / 800;
  int Y0 = tileY * 2;
  int p_thr = tid & 15, o_thr = tid >> 4;
  int y_loc = p_thr >> 3;
  int z0    = (p_thr & 7) * 5;
  int o_base = o_thr * 9;
  float acc[9][5];
  #pragma unroll
  for (int a = 0; a < 9; ++a)
    #pragma unroll
    for (int jj = 0; jj < 5; ++jj) acc[a][jj] = 0.f;
  const float* xb = x + (size_t)b * CIN * SP;
  #pragma unroll 1
  for (int ic = 0; ic < CIN / IC; ++ic) {
    #pragma unroll 1
    for (int dx = 0; dx < 5; ++dx) {
      int xs = X + dx - 2;
      if (xs < 0 || xs >= SDIM) continue;
      __syncthreads();
      for (int idx = tid; idx < IC * 6 * 44; idx += 256) {
        int i   = idx / (6 * 44);
        int rem = idx % (6 * 44);
        int yy  = rem / 44, zz = rem % 44;
        int gy = Y0 + yy - 2, gz = zz - 2;
        float v = 0.f;
        if (gy >= 0 && gy < SDIM && gz >= 0 && gz < SDIM)
          v = xb[((size_t)(ic * IC + i) * SDIM + xs) * 1600 + gy * SDIM + gz];
        x_lds[i][yy][zz] = v;
      }
      __syncthreads();
      #pragma unroll 1
      for (int dy = 0; dy < 5; ++dy) {
        const float* kbase = kw
          + ((size_t)((dx * 5 + dy) * 5) * CIN + (size_t)ic * IC) * COUT + o_base;
        #pragma unroll 1
        for (int i = 0; i < IC; ++i) {
          float xr[9];
          #pragma unroll
          for (int t = 0; t < 9; ++t) xr[t] = x_lds[i][y_loc + dy][z0 + t];
          #pragma unroll
          for (int dz = 0; dz < 5; ++dz) {
            const float* kp = kbase + ((size_t)dz * CIN + i) * COUT;
            float kv[9];
            #pragma unroll
            for (int q = 0; q < 9; ++q) kv[q] = kp[q];
            #pragma unroll
            for (int oo = 0; oo < 9; ++oo)
              #pragma unroll
              for (int j = 0; j < 5; ++j)
                acc[oo][j] = fmaf(kv[oo], xr[dz + j], acc[oo][j]);
          }
        }
      }
    }
  }
  float* ob = out + (size_t)b * COUT * SP + (size_t)X * 1600;
  #pragma unroll
  for (int oo = 0; oo < 9; ++oo) {
    int o = o_base + oo;
    #pragma unroll
    for (int j = 0; j < 5; ++j) {
      size_t idx = (size_t)o * SP + (size_t)(Y0 + y_loc) * SDIM + z0 + j;
      ob[idx] += 0.1f * acc[oo][j];
    }
  }
}

// ---------------- launcher ----------------
extern "C" void kernel_launch(void* const* d_in, const int* in_sizes, int n_in,
                              void* d_out, int out_size, void* d_ws, size_t ws_size,
                              hipStream_t stream) {
  const float* x     = (const float*)d_in[0];
  const float* w_sc0 = (const float*)d_in[1];
  const float* w_sc1 = (const float*)d_in[2];
  const float* w_tp  = (const float*)d_in[3];
  float* out = (float*)d_out;

  size_t xp_bytes  = (size_t)XP_USHORT * 2;        // 19,865,600 each
  size_t kwb_bytes = (size_t)KWB_SHORTS * 2;       // 2,304,000 each
  size_t need = 2 * xp_bytes + 2 * kwb_bytes;      // 44,339,200

  if (ws_size >= need) {
    unsigned short* xph  = (unsigned short*)d_ws;
    unsigned short* xpl  = (unsigned short*)((char*)d_ws + xp_bytes);
    unsigned short* kwbh = (unsigned short*)((char*)d_ws + 2 * xp_bytes);
    unsigned short* kwbl = (unsigned short*)((char*)d_ws + 2 * xp_bytes + kwb_bytes);

    xp_pack2<<<2 * 40 * 2 * 45, 256, 0, stream>>>(x, xph, xpl);
    build_kwb<<<(NTAP * 2 * 9 * 64 + 255) / 256, 256, 0, stream>>>(w_tp, kwbh, kwbl);
    sc_kernel<<<(2 * SP + 255) / 256, 256, 0, stream>>>(x, w_sc0, w_sc1, out);
    conv_mfma2<<<1120, 128, 0, stream>>>(xph, xpl, kwbh, kwbl, out);
  } else {
    float* kw = (float*)d_ws;
    build_kw<<<(KW_ELEMS + 255) / 256, 256, 0, stream>>>(w_tp, kw);
    sc_kernel<<<(2 * SP + 255) / 256, 256, 0, stream>>>(x, w_sc0, w_sc1, out);
    conv_kernel<<<2 * SDIM * 20, 256, 0, stream>>>(x, kw, out);
  }
}

// Round 5
// 1520.469 us; speedup vs baseline: 1.2559x; 1.2559x over previous
//
#include <hip/hip_runtime.h>
#include <math.h>

#define MUL    16
#define CIN    64
#define COUT   144
#define SDIM   40
#define SP     64000
#define NTAP   125
#define KW_ELEMS (NTAP*CIN*COUT)

// xp layout: ushort xph/xpl[b][x][ich][QROWS][32ch]
#define QROWS  1940
#define PL_STRIDE (QROWS*32)             // ushorts per (b,x,ich) plane = 62080
#define XP_USHORT (2*40*2*PL_STRIDE)     // 9,932,800 per array
#define KWB_SHORTS (NTAP*2*9*64*8)       // 1,152,000 per array

// conv tiling
#define NBLK   176
#define WIN    356                        // 176 + 4*44 + 4
#define NCHUNK 10

// ---------------- constants ----------------
#define SQ3    1.7320508075688772
#define SQ5    2.23606797749979
#define PW0    0.17677669529663687
#define PW1    0.25
#define PW2    0.3952847075210474
#define PW0_D3 0.10206207261596575
#define PW1_D3 0.14433756729740643
#define PW2_D5 0.17677669529663687
#define C_S    0.3651483716701107
#define C_H    0.31622776601683794

__device__ __constant__ double dC112[3][3][5] = {
  { {0.0, 0.0, -0.5*C_S, 0.0, -C_H},
    {0.0, C_H, 0.0,      0.0, 0.0 },
    {C_H, 0.0, 0.0,      0.0, 0.0 } },
  { {0.0, C_H, 0.0, 0.0, 0.0},
    {0.0, 0.0, C_S, 0.0, 0.0},
    {0.0, 0.0, 0.0, C_H, 0.0} },
  { {C_H, 0.0, 0.0, 0.0, 0.0},
    {0.0, 0.0, 0.0, C_H, 0.0},
    {0.0, 0.0, -0.5*C_S, 0.0, C_H} }
};

typedef __attribute__((ext_vector_type(4))) float f32x4;
typedef __attribute__((ext_vector_type(8))) short short8;
typedef __attribute__((ext_vector_type(8))) __bf16 bf16x8;

static __device__ __forceinline__ unsigned short f2bf(float f) {
  unsigned int u = __float_as_uint(f);
  unsigned int r = (u + 0x7fffu + ((u >> 16) & 1u)) >> 16;
  return (unsigned short)r;
}
static __device__ __forceinline__ float bf2f(unsigned short h) {
  return __uint_as_float(((unsigned int)h) << 16);
}
static __device__ __forceinline__ bf16x8 as_bf(short8 v) {
  union { short8 s; bf16x8 b; } u; u.s = v; return u.b;
}
static __device__ __forceinline__ short8 u4_to_s8(uint4 v) {
  union { uint4 u; short8 s; } c; c.u = v; return c.s;
}

// ---------------- weight-value function ----------------
static __device__ double kw_value(int tap, int i, int o, const float* __restrict__ w_tp) {
  int kz = tap % 5, ky = (tap / 5) % 5, kx = tap / 25;
  double lx = -1.0 + 0.5 * kx, ly = -1.0 + 0.5 * ky, lz = -1.0 + 0.5 * kz;
  double d = sqrt(lx*lx + ly*ly + lz*lz);
  double emb[5];
  #pragma unroll
  for (int t = 0; t < 5; ++t) {
    double diff = (d - (t + 1) / 6.0) * 6.0;
    double a = diff + 1.0, bb = 1.0 - diff;
    double sa = (a  > 0.0) ? exp(-1.0 / a)  : 0.0;
    double sb = (bb > 0.0) ? exp(-1.0 / bb) : 0.0;
    emb[t] = 1.14136 * exp(2.0) * sa * sb;
  }
  double inv = 1.0 / fmax(d, 1e-12);
  double ux = lx * inv, uy = ly * inv, uz = lz * inv;
  double sh1[3] = { SQ3 * ux, SQ3 * uy, SQ3 * uz };
  double sh2[5] = { SQ5 * SQ3 * ux * uz,
                    SQ5 * SQ3 * ux * uy,
                    SQ5 * (uy*uy - 0.5*(ux*ux + uz*uz)),
                    SQ5 * SQ3 * uy * uz,
                    SQ5 * 0.5 * SQ3 * (uz*uz - ux*ux) };

  #define WVAL(n, u, w) ({                                              \
      int base_ = (n)*256 + (u)*16 + (w);                               \
      double a_ = 0.0;                                                  \
      _Pragma("unroll")                                                 \
      for (int t_ = 0; t_ < 5; ++t_)                                    \
        a_ += emb[t_] * (double)w_tp[t_*1792 + base_];                  \
      (a_ * 0.08944271909999159); })

  double val;
  if (i < MUL) {
    int u = i;
    if (o < MUL) {
      val = PW0 * WVAL(0, u, o);
    } else if (o < 4 * MUL) {
      int w = (o - 16) / 3, k = (o - 16) % 3;
      val = PW1_D3 * sh1[k] * WVAL(1, u, w);
    } else {
      int w = (o - 64) / 5, k = (o - 64) % 5;
      val = PW2_D5 * sh2[k] * WVAL(2, u, w);
    }
  } else {
    int u = (i - 16) / 3, ii = (i - 16) % 3;
    if (o < MUL) {
      val = PW0_D3 * sh1[ii] * WVAL(4, u, o);
    } else if (o < 4 * MUL) {
      int w = (o - 16) / 3, k = (o - 16) % 3;
      double v = 0.0;
      if (ii == k) v += PW1_D3 * WVAL(3, u, w);
      double cs = 0.0;
      #pragma unroll
      for (int j = 0; j < 5; ++j) cs += dC112[ii][k][j] * sh2[j];
      v += PW1 * cs * WVAL(6, u, w);
      val = v;
    } else {
      int w = (o - 64) / 5, k = (o - 64) % 5;
      double cs = 0.0;
      #pragma unroll
      for (int j = 0; j < 3; ++j) cs += dC112[ii][j][k] * sh1[j];
      val = PW2 * cs * WVAL(5, u, w);
    }
  }
  return val;
}

// ---------------- MFMA-fragment weight builder ----------------
// kwbh/kwbl[(((tap*2+ich)*9+mt)*64+lane)*8 + j]
__global__ void build_kwb(const float* __restrict__ w_tp,
                          unsigned short* __restrict__ kwbh,
                          unsigned short* __restrict__ kwbl) {
  int gid = blockIdx.x * 256 + threadIdx.x;
  if (gid >= NTAP * 2 * 9 * 64) return;
  int lane = gid & 63;
  int t1 = gid >> 6;
  int mt = t1 % 9;
  int t2 = t1 / 9;
  int ich = t2 & 1;
  int tap = t2 >> 1;
  int o = mt * 16 + (lane & 15);
  unsigned short h8[8], l8[8];
  #pragma unroll
  for (int j = 0; j < 8; ++j) {
    int i = ich * 32 + 8 * (lane >> 4) + j;
    float v = (float)kw_value(tap, i, o, w_tp);
    unsigned short h = f2bf(v);
    h8[j] = h;
    l8[j] = f2bf(v - bf2f(h));
  }
  #pragma unroll
  for (int j = 0; j < 8; ++j) {
    kwbh[(size_t)gid * 8 + j] = h8[j];
    kwbl[(size_t)gid * 8 + j] = l8[j];
  }
}

// ---------------- x pack: channel-contiguous hi/lo planes ----------------
__global__ void xp_pack2(const float* __restrict__ x,
                         unsigned short* __restrict__ xph,
                         unsigned short* __restrict__ xpl) {
  __shared__ float tile[32][40];
  int bidx = blockIdx.x;
  int qy = bidx % 45;
  int t = bidx / 45;
  int ich = t & 1; t >>= 1;
  int xx = t % 40;
  int b = t / 40;
  int tid = threadIdx.x;
  size_t plane = ((size_t)(b * 40 + xx) * 2 + ich) * PL_STRIDE;
  unsigned int* dh = (unsigned int*)(xph) + plane / 2;
  unsigned int* dl = (unsigned int*)(xpl) + plane / 2;

  if (qy == 44) {               // zero rows 1936..1939
    if (tid < 64) { dh[1936 * 16 + tid] = 0u; dl[1936 * 16 + tid] = 0u; }
    return;
  }
  int y = qy - 2;
  for (int idx = tid; idx < 32 * 40; idx += 256) {
    int c = idx / 40, z = idx % 40;
    float v = 0.f;
    if (y >= 0 && y < 40)
      v = x[(((size_t)(b * 64 + ich * 32 + c) * 40 + xx) * 40 + y) * 40 + z];
    tile[c][z] = v;
  }
  __syncthreads();
  for (int idx = tid; idx < 44 * 16; idx += 256) {
    int qz = idx / 16, c2 = idx % 16;
    int z = qz - 2;
    float v0 = 0.f, v1 = 0.f;
    if (z >= 0 && z < 40) { v0 = tile[2 * c2][z]; v1 = tile[2 * c2 + 1][z]; }
    unsigned short h0 = f2bf(v0), h1 = f2bf(v1);
    unsigned short l0 = f2bf(v0 - bf2f(h0)), l1 = f2bf(v1 - bf2f(h1));
    int q = qy * 44 + qz;
    dh[q * 16 + c2] = ((unsigned int)h1 << 16) | h0;
    dl[q * 16 + c2] = ((unsigned int)l1 << 16) | l0;
  }
}

// ---------------- self-connection ----------------
__global__ void sc_kernel(const float* __restrict__ x,
                          const float* __restrict__ w0,
                          const float* __restrict__ w1,
                          float* __restrict__ out) {
  int gid = blockIdx.x * 256 + threadIdx.x;
  if (gid >= 2 * SP) return;
  int b = gid / SP, p = gid % SP;
  const float* xb = x + (size_t)b * CIN * SP + p;
  float xv[64];
  #pragma unroll
  for (int c = 0; c < 64; ++c) xv[c] = xb[(size_t)c * SP];
  float* ob = out + (size_t)b * COUT * SP + p;
  #pragma unroll
  for (int w = 0; w < 16; ++w) {
    float s = 0.f;
    #pragma unroll
    for (int u = 0; u < 16; ++u) s = fmaf(w0[u * 16 + w], xv[u], s);
    ob[(size_t)w * SP] = 0.25f * s;
  }
  #pragma unroll
  for (int w = 0; w < 16; ++w) {
    #pragma unroll
    for (int i2 = 0; i2 < 3; ++i2) {
      float s = 0.f;
      #pragma unroll
      for (int u = 0; u < 16; ++u) s = fmaf(w1[u * 16 + w], xv[16 + u * 3 + i2], s);
      ob[(size_t)(16 + w * 3 + i2) * SP] = 0.25f * s;
    }
  }
  #pragma unroll
  for (int o = 64; o < 144; ++o) ob[(size_t)o * SP] = 0.f;
}

// ---------------- MFMA conv: 4 waves, nt=3, N=176/block, pipelined ----------------
// grid = 800 = 8 XCD * 100; logical = bX*10 + chunk
#define LOADB(BH, BL, QB, DZ)                                              \
  do {                                                                     \
    _Pragma("unroll")                                                      \
    for (int nt_ = 0; nt_ < 3; ++nt_) {                                    \
      int q_ = (QB)[nt_] + (DZ);                                           \
      int off_ = q_ * 16 + (((g ^ ((q_ >> 1) & 3))) << 2);                 \
      (BH)[nt_] = u4_to_s8(*(const uint4*)(xh32 + off_));                  \
      (BL)[nt_] = u4_to_s8(*(const uint4*)(xl32 + off_));                  \
    }                                                                      \
  } while (0)

__global__ __launch_bounds__(256, 2)
void conv_mfma3(const unsigned short* __restrict__ xph,
                const unsigned short* __restrict__ xpl,
                const unsigned short* __restrict__ kwbh,
                const unsigned short* __restrict__ kwbl,
                float* __restrict__ out) {
  __shared__ __align__(16) unsigned int xh32[WIN * 16];   // 22.8 KB
  __shared__ __align__(16) unsigned int xl32[WIN * 16];   // 22.8 KB

  int tid = threadIdx.x;
  int bid = blockIdx.x;
  int logical = (bid & 7) * 100 + (bid >> 3);     // XCD-grouped
  int bX = logical / NCHUNK;
  int chunk = logical - bX * NCHUNK;
  int b = bX / 40, X = bX % 40;
  int p0 = chunk * NBLK;

  int wid = tid >> 6, lane = tid & 63;
  int l15 = lane & 15, g = lane >> 4;

  int tb[3]; bool realt[3]; int ptl[3];
  #pragma unroll
  for (int nt = 0; nt < 3; ++nt) {
    int slot = wid * 3 + nt;
    realt[nt] = (slot <= 10);
    int t = slot > 10 ? 10 : slot;
    ptl[nt] = p0 + t * 16;
    tb[nt] = t * 16 + l15;
  }

  f32x4 acc[9][3];
  #pragma unroll
  for (int mt = 0; mt < 9; ++mt)
    #pragma unroll
    for (int nt = 0; nt < 3; ++nt) acc[mt][nt] = (f32x4)0.f;

  #pragma unroll 1
  for (int dx = 0; dx < 5; ++dx) {
    int xs = X + dx - 2;
    if (xs < 0 || xs >= 40) continue;     // uniform
    #pragma unroll 1
    for (int ich = 0; ich < 2; ++ich) {
      __syncthreads();
      {
        size_t plane = ((size_t)(b * 40 + xs) * 2 + ich) * PL_STRIDE;
        const unsigned int* sh = (const unsigned int*)xph + plane / 2 + (size_t)p0 * 16;
        const unsigned int* sl = (const unsigned int*)xpl + plane / 2 + (size_t)p0 * 16;
        #pragma unroll 1
        for (int idx = tid; idx < WIN * 4; idx += 256) {
          int q = idx >> 2, s4 = idx & 3;
          uint4 vh = *(const uint4*)(sh + q * 16 + s4 * 4);
          uint4 vl = *(const uint4*)(sl + q * 16 + s4 * 4);
          int dst = q * 16 + ((s4 ^ ((q >> 1) & 3)) << 2);
          *(uint4*)(xh32 + dst) = vh;
          *(uint4*)(xl32 + dst) = vl;
        }
      }
      __syncthreads();
      #pragma unroll 1
      for (int dy = 0; dy < 5; ++dy) {
        int qb[3];
        #pragma unroll
        for (int nt = 0; nt < 3; ++nt) qb[nt] = tb[nt] + dy * 44;
        short8 bh[3], bl[3];
        LOADB(bh, bl, qb, 0);
        #pragma unroll 1
        for (int dz = 0; dz < 5; ++dz) {
          short8 nbh[3], nbl[3];
          if (dz < 4) LOADB(nbh, nbl, qb, dz + 1);
          int tap = (dx * 5 + dy) * 5 + dz;
          const short8* ah_p = (const short8*)kwbh + ((size_t)(tap * 2 + ich) * 9) * 64 + lane;
          const short8* al_p = (const short8*)kwbl + ((size_t)(tap * 2 + ich) * 9) * 64 + lane;
          short8 ah = ah_p[0], al = al_p[0];
          #pragma unroll
          for (int mt = 0; mt < 9; ++mt) {
            short8 ahn, aln;
            if (mt < 8) { ahn = ah_p[(mt + 1) * 64]; aln = al_p[(mt + 1) * 64]; }
            acc[mt][0] = __builtin_amdgcn_mfma_f32_16x16x32_bf16(as_bf(ah), as_bf(bh[0]), acc[mt][0], 0, 0, 0);
            acc[mt][1] = __builtin_amdgcn_mfma_f32_16x16x32_bf16(as_bf(ah), as_bf(bh[1]), acc[mt][1], 0, 0, 0);
            acc[mt][2] = __builtin_amdgcn_mfma_f32_16x16x32_bf16(as_bf(ah), as_bf(bh[2]), acc[mt][2], 0, 0, 0);
            acc[mt][0] = __builtin_amdgcn_mfma_f32_16x16x32_bf16(as_bf(ah), as_bf(bl[0]), acc[mt][0], 0, 0, 0);
            acc[mt][1] = __builtin_amdgcn_mfma_f32_16x16x32_bf16(as_bf(ah), as_bf(bl[1]), acc[mt][1], 0, 0, 0);
            acc[mt][2] = __builtin_amdgcn_mfma_f32_16x16x32_bf16(as_bf(ah), as_bf(bl[2]), acc[mt][2], 0, 0, 0);
            acc[mt][0] = __builtin_amdgcn_mfma_f32_16x16x32_bf16(as_bf(al), as_bf(bh[0]), acc[mt][0], 0, 0, 0);
            acc[mt][1] = __builtin_amdgcn_mfma_f32_16x16x32_bf16(as_bf(al), as_bf(bh[1]), acc[mt][1], 0, 0, 0);
            acc[mt][2] = __builtin_amdgcn_mfma_f32_16x16x32_bf16(as_bf(al), as_bf(bh[2]), acc[mt][2], 0, 0, 0);
            ah = ahn; al = aln;
          }
          #pragma unroll
          for (int nt = 0; nt < 3; ++nt) { bh[nt] = nbh[nt]; bl[nt] = nbl[nt]; }
        }
      }
    }
  }

  float* ob = out + (size_t)b * COUT * SP + (size_t)X * 1600;
  #pragma unroll
  for (int mt = 0; mt < 9; ++mt) {
    #pragma unroll
    for (int nt = 0; nt < 3; ++nt) {
      if (!realt[nt]) continue;
      int p = ptl[nt] + l15;
      int y = p / 44, z = p - y * 44;
      if (z < 40) {
        #pragma unroll
        for (int r = 0; r < 4; ++r) {
          int o = mt * 16 + g * 4 + r;
          ob[(size_t)o * SP + y * 40 + z] += 0.1f * acc[mt][nt][r];
        }
      }
    }
  }
}

// ---------------- fp32 fallback path ----------------
__global__ void build_kw(const float* __restrict__ w_tp, float* __restrict__ kw) {
  int gid = blockIdx.x * 256 + threadIdx.x;
  if (gid >= KW_ELEMS) return;
  int o   = gid % COUT;
  int i   = (gid / COUT) % CIN;
  int tap = gid / (COUT * CIN);
  kw[gid] = (float)kw_value(tap, i, o, w_tp);
}

#define IC 8
__global__ __launch_bounds__(256, 4)
void conv_kernel(const float* __restrict__ x,
                 const float* __restrict__ kw,
                 float* __restrict__ out) {
  __shared__ float x_lds[IC][6][44];
  int tid = threadIdx.x;
  int bid = blockIdx.x;
  int tileY = bid % 20;
  int X     = (bid / 20) % SDIM;
  int b     = bid / 800;
  int Y0 = tileY * 2;
  int p_thr = tid & 15, o_thr = tid >> 4;
  int y_loc = p_thr >> 3;
  int z0    = (p_thr & 7) * 5;
  int o_base = o_thr * 9;
  float acc[9][5];
  #pragma unroll
  for (int a = 0; a < 9; ++a)
    #pragma unroll
    for (int jj = 0; jj < 5; ++jj) acc[a][jj] = 0.f;
  const float* xb = x + (size_t)b * CIN * SP;
  #pragma unroll 1
  for (int ic = 0; ic < CIN / IC; ++ic) {
    #pragma unroll 1
    for (int dx = 0; dx < 5; ++dx) {
      int xs = X + dx - 2;
      if (xs < 0 || xs >= SDIM) continue;
      __syncthreads();
      for (int idx = tid; idx < IC * 6 * 44; idx += 256) {
        int i   = idx / (6 * 44);
        int rem = idx % (6 * 44);
        int yy  = rem / 44, zz = rem % 44;
        int gy = Y0 + yy - 2, gz = zz - 2;
        float v = 0.f;
        if (gy >= 0 && gy < SDIM && gz >= 0 && gz < SDIM)
          v = xb[((size_t)(ic * IC + i) * SDIM + xs) * 1600 + gy * SDIM + gz];
        x_lds[i][yy][zz] = v;
      }
      __syncthreads();
      #pragma unroll 1
      for (int dy = 0; dy < 5; ++dy) {
        const float* kbase = kw
          + ((size_t)((dx * 5 + dy) * 5) * CIN + (size_t)ic * IC) * COUT + o_base;
        #pragma unroll 1
        for (int i = 0; i < IC; ++i) {
          float xr[9];
          #pragma unroll
          for (int t = 0; t < 9; ++t) xr[t] = x_lds[i][y_loc + dy][z0 + t];
          #pragma unroll
          for (int dz = 0; dz < 5; ++dz) {
            const float* kp = kbase + ((size_t)dz * CIN + i) * COUT;
            float kv[9];
            #pragma unroll
            for (int q = 0; q < 9; ++q) kv[q] = kp[q];
            #pragma unroll
            for (int oo = 0; oo < 9; ++oo)
              #pragma unroll
              for (int j = 0; j < 5; ++j)
                acc[oo][j] = fmaf(kv[oo], xr[dz + j], acc[oo][j]);
          }
        }
      }
    }
  }
  float* ob = out + (size_t)b * COUT * SP + (size_t)X * 1600;
  #pragma unroll
  for (int oo = 0; oo < 9; ++oo) {
    int o = o_base + oo;
    #pragma unroll
    for (int j = 0; j < 5; ++j) {
      size_t idx = (size_t)o * SP + (size_t)(Y0 + y_loc) * SDIM + z0 + j;
      ob[idx] += 0.1f * acc[oo][j];
    }
  }
}

// ---------------- launcher ----------------
extern "C" void kernel_launch(void* const* d_in, const int* in_sizes, int n_in,
                              void* d_out, int out_size, void* d_ws, size_t ws_size,
                              hipStream_t stream) {
  const float* x     = (const float*)d_in[0];
  const float* w_sc0 = (const float*)d_in[1];
  const float* w_sc1 = (const float*)d_in[2];
  const float* w_tp  = (const float*)d_in[3];
  float* out = (float*)d_out;

  size_t xp_bytes  = (size_t)XP_USHORT * 2;        // 19,865,600 each
  size_t kwb_bytes = (size_t)KWB_SHORTS * 2;       // 2,304,000 each
  size_t need = 2 * xp_bytes + 2 * kwb_bytes;      // 44,339,200

  if (ws_size >= need) {
    unsigned short* xph  = (unsigned short*)d_ws;
    unsigned short* xpl  = (unsigned short*)((char*)d_ws + xp_bytes);
    unsigned short* kwbh = (unsigned short*)((char*)d_ws + 2 * xp_bytes);
    unsigned short* kwbl = (unsigned short*)((char*)d_ws + 2 * xp_bytes + kwb_bytes);

    xp_pack2<<<2 * 40 * 2 * 45, 256, 0, stream>>>(x, xph, xpl);
    build_kwb<<<(NTAP * 2 * 9 * 64 + 255) / 256, 256, 0, stream>>>(w_tp, kwbh, kwbl);
    sc_kernel<<<(2 * SP + 255) / 256, 256, 0, stream>>>(x, w_sc0, w_sc1, out);
    conv_mfma3<<<800, 256, 0, stream>>>(xph, xpl, kwbh, kwbl, out);
  } else {
    float* kw = (float*)d_ws;
    build_kw<<<(KW_ELEMS + 255) / 256, 256, 0, stream>>>(w_tp, kw);
    sc_kernel<<<(2 * SP + 255) / 256, 256, 0, stream>>>(x, w_sc0, w_sc1, out);
    conv_kernel<<<2 * SDIM * 20, 256, 0, stream>>>(x, kw, out);
  }
}